// Round 5
// baseline (94.320 us; speedup 1.0000x reference)
//
#include <hip/hip_runtime.h>

#define NPIX 4096
#define NT 1024
#define PPT (NPIX / NT)   // 4 per thread
#define EMPTY 0xFFFFFFFFu
#define FLAGMAGIC 0x00C0FFEEu

__global__ void ph_zero_kernel(float* out) { out[0] = 0.0f; }

__device__ __forceinline__ float kval(unsigned k) {
  unsigned u = (k & 0x80000000u) ? (k & 0x7FFFFFFFu) : ~k;
  return __uint_as_float(u);
}

__global__ __launch_bounds__(NT) void ph_pass_kernel(const float* __restrict__ x,
                                                     float* __restrict__ out,
                                                     unsigned long long* __restrict__ ws64,
                                                     int use_ws) {
  // One 64 KB pool, phase-aliased:
  //  [0,32K)  : hash (hkey 16K | hval 16K) -> compacted edge list (unsorted)
  //  [32K,48K): key32 u32[4096]            -> clobbered by node records
  //  [48K,56K): label u16[4096]            -> clobbered by node records
  //  [32K,64K): node u64[4096] = creatorKey<<32 | parent   (union-find phase)
  __shared__ unsigned long long pool[2 * NPIX];
  __shared__ unsigned long long claim64[NPIX]; // 32 KB seq-tagged claim cells
  __shared__ unsigned long long wred[32];  // wave staging: [0..15] raw, [16..31] scanned
  __shared__ int s_chg[13];                // watershed + union-round flags
  __shared__ double s_sum[16];             // block reduction staging
  __shared__ float s_max[16];
  __shared__ int s_cnt[16];

  unsigned long long* sbuf = pool;
  unsigned* hkey = (unsigned*)pool;
  unsigned* hval = hkey + NPIX;
  unsigned* key32 = (unsigned*)(pool + NPIX);
  unsigned short* label = (unsigned short*)(pool + NPIX + NPIX / 2);
  unsigned long long* node = pool + NPIX;

  const int blk = blockIdx.x;            // 24 blocks: b(4) x c(3) x pass(2)
  const int b = blk / 6;
  const int rem = blk % 6;
  const int c = (rem >> 1) + 1;          // classes 1..3
  const int pass = rem & 1;              // 0 = sublevel 8-conn (H0), 1 = superlevel 4-conn (H1)
  const float* img = x + (size_t)(b * 4 + c) * NPIX;
  const int tid = threadIdx.x;
  const int lane = tid & 63, wid = tid >> 6;
  const int ndirs = pass ? 4 : 8;
  const int drr[8] = {-1, 1, 0, 0, -1, -1, 1, 1};
  const int dcc[8] = { 0, 0,-1, 1, -1,  1, -1, 1};

  // --- phase 1: monotone keys (pass 1 negates); hash+claim init folded; min ---
  if (tid < 13) s_chg[tid] = 0;
  unsigned lmin = EMPTY;
  for (int i = tid; i < NPIX; i += NT) {
    float f = img[i];
    if (pass) f = -f;
    unsigned u = __float_as_uint(f);
    unsigned k = (u & 0x80000000u) ? ~u : (u | 0x80000000u);
    key32[i] = k;
    pool[i] = ~0ull;                     // hkey/hval = EMPTY (region [0,32K))
    claim64[i] = 0ull;                   // claims: any real claim (seq>=1) wins
    lmin = min(lmin, k);
  }
  for (int off = 32; off > 0; off >>= 1)
    lmin = min(lmin, (unsigned)__shfl_xor((int)lmin, off));
  if (lane == 0) wred[wid] = lmin;
  __syncthreads();
  unsigned vmink = (unsigned)wred[0];
  #pragma unroll
  for (int w = 1; w < 16; w++) vmink = min(vmink, (unsigned)wred[w]);

  // --- phase 2: watershed pointers + converging 4-hop pointer jumping.
  //     Each round stores the 4-hops-up ancestor -> distance-to-root shrinks
  //     ~4x/round; 4^6 = 4096 >= any path, so 6 rounds guarantee convergence.
  //     Racy mixed reads only jump further up-chain (ancestor-monotone). ---
  for (int i = tid; i < NPIX; i += NT) {
    unsigned long long best = ((unsigned long long)key32[i] << 32) | (unsigned)i;
    int bestnb = i;
    int r = i >> 6, cc = i & 63;
    for (int d = 0; d < ndirs; d++) {
      int rr = r + drr[d], c2 = cc + dcc[d];
      if ((unsigned)rr >= 64u || (unsigned)c2 >= 64u) continue;
      int nb = (rr << 6) | c2;
      unsigned long long pn = ((unsigned long long)key32[nb] << 32) | (unsigned)nb;
      if (pn < best) { best = pn; bestnb = nb; }
    }
    label[i] = (unsigned short)bestnb;
  }
  __syncthreads();
  for (int round = 0; round < 6; round++) {
    bool changed = false;
    for (int i = tid; i < NPIX; i += NT) {
      unsigned short l = label[i];
      unsigned short l2 = label[l];
      unsigned short l3 = label[l2];
      unsigned short l4 = label[l3];
      if (l4 != l) { label[i] = l4; changed = true; }
    }
    if (changed) s_chg[round] = 1;
    __syncthreads();
    if (!s_chg[round]) break;                  // block-uniform
  }

  // --- phase 3: inter-basin edges deduped to min weight per basin pair ---
  const int pdr[4] = {1, 0, 1,  1};
  const int pdc[4] = {0, 1, 1, -1};
  const int npd = pass ? 2 : 4;
  for (int i = tid; i < NPIX; i += NT) {
    int r = i >> 6, cc = i & 63;
    unsigned la = label[i];
    unsigned ki = key32[i];
    for (int d = 0; d < npd; d++) {
      int rr = r + pdr[d], c2 = cc + pdc[d];
      if ((unsigned)rr >= 64u || (unsigned)c2 >= 64u) continue;
      int nb = (rr << 6) | c2;
      unsigned lb = label[nb];
      if (lb == la) continue;
      unsigned wkey = max(ki, key32[nb]);      // weight = max endpoint key
      unsigned pk = la < lb ? ((la << 12) | lb) : ((lb << 12) | la);
      unsigned h = (pk * 2654435761u) >> 20;
      while (true) {
        unsigned old = atomicCAS(&hkey[h], EMPTY, pk);
        if (old == EMPTY || old == pk) { atomicMin(&hval[h], wkey); break; }
        h = (h + 1) & (NPIX - 1);
      }
    }
  }
  __syncthreads();

  // --- phase 4: compact hash to an (unsorted) edge list; node records ---
  unsigned long long item[PPT];
  unsigned mykeys[PPT];
  int cnt = 0;
  #pragma unroll
  for (int q = 0; q < PPT; q++) {
    int s = tid * PPT + q;
    unsigned pk = hkey[s];
    if (pk != EMPTY) item[cnt++] = (((unsigned long long)hval[s]) << 32) | pk;
  }
  #pragma unroll
  for (int t = 0; t < PPT; t++) mykeys[t] = key32[tid + t * NT];
  __syncthreads();                       // all reads of pool[0..56K) done
  unsigned inc = (unsigned)cnt;
  for (int off = 1; off < 64; off <<= 1) {   // intra-wave inclusive scan
    unsigned v = __shfl_up(inc, off);
    if (lane >= off) inc += v;
  }
  if (lane == 63) wred[wid] = inc;
  __syncthreads();
  if (wid == 0) {                        // scan the 16 wave totals in wave 0
    unsigned wv = (lane < 16) ? (unsigned)wred[lane] : 0u;
    for (int off = 1; off < 16; off <<= 1) {
      unsigned v = __shfl_up(wv, off);
      if (lane >= off) wv += v;
    }
    if (lane < 16) wred[16 + lane] = wv;
  }
  __syncthreads();
  const int M = (int)wred[31];
  const int base0 = (int)((wid ? (unsigned)wred[16 + wid - 1] : 0u) + inc) - cnt;
  for (int q = 0; q < cnt; q++) sbuf[base0 + q] = item[q];
  #pragma unroll
  for (int t = 0; t < PPT; t++) {
    int i = tid + t * NT;
    node[i] = (((unsigned long long)mykeys[t]) << 32) | (unsigned)i;  // singleton
  }
  if (tid < 2) s_chg[tid] = 0;           // re-zero parity flags for phase 6
  __syncthreads();

  // --- phase 6: ALL-AT-ONCE parallel Kruskal (claim BOTH roots, test YOUNG),
  //     2 barriers/round. Round t layout:
  //       [refind+claim(t) segment] -> B_pre -> [win-test+commit+vote(t),
  //       reset flag(t+1)] -> B_mid -> exit check on flag(t) -> loop.
  //     Claims(t) all precede B_pre; commits(t) all in (B_pre,B_mid); refinds
  //     of t+1 read post-commit node[] after B_mid. Parity flags s_chg[t&1]
  //     separate vote(t) from reset(t+1). Winner per cell unique (max claim,
  //     ids distinct). Read-filter before atomicMax: skipping a claim that
  //     cannot raise the max is semantics-free; stale-low reads fall through
  //     to the atomic. One ghost round possible at exit (cycle edges vote
  //     before discovering cycle status) — 2 barriers, harmless. ---
  double sumsq = 0.0;
  float maxp = 0.0f;
  int pcnt = 0;
  unsigned ewk[PPT], exa[PPT], exb[PPT];
  unsigned long long erA[PPT], erB[PPT];
  unsigned pmask = 0;
  #pragma unroll
  for (int q = 0; q < PPT; q++) {
    const int j = tid + q * NT;
    if (j < M) {
      const unsigned long long e = sbuf[j];
      ewk[q] = (unsigned)(e >> 32);
      const unsigned pk = (unsigned)(e & 0xFFFFFFu);
      unsigned xa = pk >> 12, xb = pk & 0xFFFu;   // basin roots (singletons now)
      exa[q] = xa; exb[q] = xb;
      erA[q] = node[xa]; erB[q] = node[xb];
      pmask |= 1u << q;                  // distinct basins by construction
    }
  }
  unsigned long long seqtag = (1ull << 44);
  #pragma unroll
  for (int q = 0; q < PPT; q++) {        // prime claims for round 1
    if (pmask & (1u << q)) {
      const int j = tid + q * NT;
      const unsigned long long myval =
          seqtag | (((unsigned long long)(~ewk[q])) << 12) | (unsigned)j;
      unsigned young, elder;
      if (erA[q] < erB[q]) { elder = exa[q]; young = exb[q]; }
      else                 { elder = exb[q]; young = exa[q]; }
      if (claim64[young] < myval) atomicMax(&claim64[young], myval);
      if (claim64[elder] < myval) atomicMax(&claim64[elder], myval);
    }
  }
  int rt = 1;
  while (true) {
    __syncthreads();                     // B_pre: claims(rt) visible
    #pragma unroll
    for (int q = 0; q < PPT; q++) {      // win-test + commit
      if (pmask & (1u << q)) {
        const int j = tid + q * NT;
        const unsigned long long myval =
            seqtag | (((unsigned long long)(~ewk[q])) << 12) | (unsigned)j;
        unsigned young, elder;
        unsigned long long yrec;
        if (erA[q] < erB[q]) { elder = exa[q]; young = exb[q]; yrec = erB[q]; }
        else                 { elder = exb[q]; young = exa[q]; yrec = erA[q]; }
        if (claim64[young] == myval) {
          const unsigned ky = (unsigned)(yrec >> 32);
          if (ewk[q] > ky) {             // strictly positive persistence
            float pers = kval(ewk[q]) - kval(ky);
            sumsq += (double)pers * (double)pers;
            maxp = fmaxf(maxp, pers);
            pcnt++;
          }
          node[young] = (yrec & 0xFFFFFFFF00000000ull) | elder;
          pmask &= ~(1u << q);
        }
      }
    }
    if (pmask) s_chg[rt & 1] = 1;        // vote: still pending
    if (tid == 0) s_chg[(rt + 1) & 1] = 0;   // reset next round's flag
    __syncthreads();                     // B_mid: commits + votes visible
    if (!s_chg[rt & 1]) break;           // block-uniform exit
    rt++; seqtag += (1ull << 44);
    #pragma unroll
    for (int q = 0; q < PPT; q++) {      // refind + re-claim(rt)
      if (pmask & (1u << q)) {
        unsigned xa = exa[q], xb = exb[q];
        unsigned long long recA = node[xa], recB = node[xb];
        while ((unsigned)recA != xa) { xa = (unsigned)recA; recA = node[xa]; }
        while ((unsigned)recB != xb) { xb = (unsigned)recB; recB = node[xb]; }
        exa[q] = xa; exb[q] = xb; erA[q] = recA; erB[q] = recB;
        if (xa == xb) {
          pmask &= ~(1u << q);           // became a cycle edge: drop
        } else {
          const int j = tid + q * NT;
          const unsigned long long myval =
              seqtag | (((unsigned long long)(~ewk[q])) << 12) | (unsigned)j;
          unsigned young, elder;
          if (recA < recB) { elder = xa; young = xb; }
          else             { elder = xb; young = xa; }
          if (claim64[young] < myval) atomicMax(&claim64[young], myval);
          if (claim64[elder] < myval) atomicMax(&claim64[elder], myval);
        }
      }
    }
  }
  // block-wide reduction of (sumsq, maxp, pcnt): wave shfl then LDS combine
  for (int off = 32; off > 0; off >>= 1) {
    sumsq += __shfl_xor(sumsq, off);
    maxp = fmaxf(maxp, __shfl_xor(maxp, off));
    pcnt += __shfl_xor(pcnt, off);
  }
  if (lane == 0) { s_sum[wid] = sumsq; s_max[wid] = maxp; s_cnt[wid] = pcnt; }
  __syncthreads();

  // --- phase 7: per-block contribution ---
  float contrib = 0.0f;
  if (tid == 0) {
    #pragma unroll
    for (int w = 1; w < 16; w++) {
      sumsq += s_sum[w];
      maxp = fmaxf(maxp, s_max[w]);
      pcnt += s_cnt[w];
    }
    if (pass == 0) {
      const int nf0 = (c == 3) ? 2 : 1;      // TOPO H0: c1->1, c2->1, c3->2
      float vmin = kval(vmink);              // essential birth = global min
      if (nf0 == 1) {
        contrib = vmin * vmin + (float)sumsq;
      } else if (pcnt >= 1) {
        contrib = vmin * vmin + (1.0f - maxp) * (1.0f - maxp)
                + (float)(sumsq - (double)maxp * (double)maxp);
      } else {
        contrib = vmin * vmin + 1.0f;
      }
    } else {
      const int nf1 = (c == 2) ? 1 : 0;      // TOPO H1: c1->0, c2->1, c3->0
      if (nf1 == 0) contrib = (float)sumsq;
      else contrib = (pcnt >= 1)
        ? ((1.0f - maxp) * (1.0f - maxp) + (float)(sumsq - (double)maxp * (double)maxp))
        : 1.0f;
    }
    contrib *= 0.25f;                        // / B, B = 4
    if (use_ws) {
      // publish (value<<32 | magic) in one device-scope atomic — no fence needed
      atomicExch(&ws64[blk],
                 (((unsigned long long)__float_as_uint(contrib)) << 32) | FLAGMAGIC);
    } else {
      atomicAdd(out, contrib);               // out pre-zeroed by ph_zero_kernel
    }
  }
  // --- block 0 wave 0: gather all 24 contributions, write out ---
  if (use_ws && blk == 0 && wid == 0) {
    float v = 0.0f;
    if (lane < 24) {
      while (true) {
        unsigned long long r = atomicAdd(&ws64[lane], 0ull);  // device-coherent read
        if ((unsigned)r == FLAGMAGIC) { v = __uint_as_float((unsigned)(r >> 32)); break; }
      }
    }
    for (int off = 32; off > 0; off >>= 1) v += __shfl_xor(v, off);
    if (lane == 0) out[0] = v;
  }
}

extern "C" void kernel_launch(void* const* d_in, const int* in_sizes, int n_in,
                              void* d_out, int out_size, void* d_ws, size_t ws_size,
                              hipStream_t stream) {
  const float* x = (const float*)d_in[0];
  float* out = (float*)d_out;
  if (ws_size >= 24 * sizeof(unsigned long long)) {
    ph_pass_kernel<<<24, NT, 0, stream>>>(x, out, (unsigned long long*)d_ws, 1);
  } else {
    ph_zero_kernel<<<1, 1, 0, stream>>>(out);
    ph_pass_kernel<<<24, NT, 0, stream>>>(x, out, nullptr, 0);
  }
}